// Round 7
// baseline (303.207 us; speedup 1.0000x reference)
//
#include <hip/hip_runtime.h>
#include <cstdint>
#include <cstddef>

typedef __bf16 bf16x8 __attribute__((ext_vector_type(8)));
typedef float  f32x4  __attribute__((ext_vector_type(4)));

#define N_ROWS 8192
#define KDIM   256
#define TEMP_INV 2.0f
#define LOG2E  1.4426950408889634f
#define EXPC   (TEMP_INV * LOG2E)

__device__ __forceinline__ ushort f2bf(float x) {
    uint32_t u = __float_as_uint(x);
    u += 0x7fffu + ((u >> 16) & 1u);
    return (ushort)(u >> 16);
}

// ---------------- Kernel A: label ranking / permutation (1 block, 1024 thr)
__global__ __launch_bounds__(1024) void build_perm(const int* __restrict__ label,
        int* __restrict__ perm, int* __restrict__ labelPerm,
        int* __restrict__ classStart, int* __restrict__ cumTiles,
        unsigned int* __restrict__ counter)
{
    __shared__ unsigned short lcnt[1024][10];
    __shared__ int cstart[11];
    __shared__ int ccount[10];
    const int tid = threadIdx.x;
    const int wave = tid >> 6, lane = tid & 63;

    if (tid == 0) counter[0] = 0u;   // re-arm the phase3 tail every call

    int lab[8];
    #pragma unroll
    for (int j = 0; j < 8; ++j) {
        int c = label[tid + j * 1024];
        lab[j] = (c < 0) ? 0 : (c > 9 ? 9 : c);
    }
    unsigned short loc[10] = {0,0,0,0,0,0,0,0,0,0};
    #pragma unroll
    for (int j = 0; j < 8; ++j) loc[lab[j]]++;
    #pragma unroll
    for (int c = 0; c < 10; ++c) lcnt[tid][c] = loc[c];
    __syncthreads();

    if (wave < 10) {  // one wave per class: scan 1024 counts
        const int c = wave;
        int s[16]; int tot = 0;
        #pragma unroll
        for (int m = 0; m < 16; ++m) { s[m] = lcnt[lane * 16 + m][c]; tot += s[m]; }
        int incl = tot;
        #pragma unroll
        for (int d = 1; d < 64; d <<= 1) {
            int up = __shfl_up(incl, d, 64);
            if (lane >= d) incl += up;
        }
        int run = incl - tot;
        #pragma unroll
        for (int m = 0; m < 16; ++m) { lcnt[lane * 16 + m][c] = (unsigned short)run; run += s[m]; }
        if (lane == 63) ccount[c] = incl;
    }
    __syncthreads();

    if (tid == 0) {
        int run = 0, runT = 0;
        for (int c = 0; c < 10; ++c) {
            cstart[c] = run; classStart[c] = run;
            int tpc = (ccount[c] + 127) >> 7;
            cumTiles[c] = runT;
            run  += ccount[c];
            runT += tpc * tpc;
        }
        cstart[10] = run; classStart[10] = run; cumTiles[10] = runT;
    }
    __syncthreads();

    int ofs[10];
    #pragma unroll
    for (int c = 0; c < 10; ++c) ofs[c] = lcnt[tid][c];
    #pragma unroll
    for (int j = 0; j < 8; ++j) {
        int c = lab[j];
        int pos = cstart[c] + ofs[c]++;
        perm[pos] = tid + j * 1024;
        labelPerm[pos] = c;
    }
}

// ---------------- Kernel B: normalize + permute + bf16 cast (4 rows / block)
__global__ __launch_bounds__(256) void normalize_rows(const float* __restrict__ logits,
        const int* __restrict__ perm, ushort* __restrict__ xn)
{
    const int p = blockIdx.x * 4 + (threadIdx.x >> 6);
    const int lane = threadIdx.x & 63;
    const int old = perm[p];
    float4 v = reinterpret_cast<const float4*>(logits + (size_t)old * KDIM)[lane];
    float ss = v.x*v.x + v.y*v.y + v.z*v.z + v.w*v.w;
    #pragma unroll
    for (int off = 32; off >= 1; off >>= 1) ss += __shfl_xor(ss, off, 64);
    float inv = 1.0f / fmaxf(sqrtf(ss), 1e-8f);
    ushort4 o;
    o.x = f2bf(v.x * inv); o.y = f2bf(v.y * inv);
    o.z = f2bf(v.z * inv); o.w = f2bf(v.w * inv);
    reinterpret_cast<ushort4*>(xn + (size_t)p * KDIM)[lane] = o;
}

// ---------------- 4-wave 128-tile GEMM core (validated rounds 3-4) ----------
__device__ __forceinline__ void stage_tiles(const ushort* __restrict__ xn,
        int rowBase, int colBase, int kb, ushort* As, ushort* Bs, int wave, int lane)
{
    #pragma unroll
    for (int it = 0; it < 4; ++it) {
        int ci = it * 256 + wave * 64 + lane;
        int row = ci >> 3;
        int c = (ci & 7) ^ (row & 7);                  // T2 pre-swizzled source
        const ushort* gA = xn + (size_t)(rowBase + row) * KDIM + kb + c * 8;
        const ushort* gB = xn + (size_t)(colBase + row) * KDIM + kb + c * 8;
        ushort* lA = As + (size_t)(it * 256 + wave * 64) * 8;
        ushort* lB = Bs + (size_t)(it * 256 + wave * 64) * 8;
        __builtin_amdgcn_global_load_lds((const __attribute__((address_space(1))) void*)gA,
                                         (__attribute__((address_space(3))) void*)lA, 16, 0, 0);
        __builtin_amdgcn_global_load_lds((const __attribute__((address_space(1))) void*)gB,
                                         (__attribute__((address_space(3))) void*)lB, 16, 0, 0);
    }
}

__device__ __forceinline__ void read_frags(const ushort* As, const ushort* Bs,
        bf16x8 (&a)[2][4], bf16x8 (&b)[2][4], int wave, int lane)
{
    const int wr = wave >> 1, wc = wave & 1;
    const int lrow = lane & 15, kgrp = lane >> 4;
    #pragma unroll
    for (int kk = 0; kk < 2; ++kk) {
        const int c = kk * 4 + kgrp;
        #pragma unroll
        for (int mi = 0; mi < 4; ++mi) {
            const int row = wr*64 + mi*16 + lrow;
            a[kk][mi] = *reinterpret_cast<const bf16x8*>(As + (size_t)row * 64 + ((c ^ (row & 7)) * 8));
        }
        #pragma unroll
        for (int ni = 0; ni < 4; ++ni) {
            const int row = wc*64 + ni*16 + lrow;
            b[kk][ni] = *reinterpret_cast<const bf16x8*>(Bs + (size_t)row * 64 + ((c ^ (row & 7)) * 8));
        }
    }
}

__device__ __forceinline__ void mfma_frags(bf16x8 (&a)[2][4], bf16x8 (&b)[2][4],
                                           f32x4 (&acc)[4][4])
{
    #pragma unroll
    for (int kk = 0; kk < 2; ++kk)
        #pragma unroll
        for (int mi = 0; mi < 4; ++mi)
            #pragma unroll
            for (int ni = 0; ni < 4; ++ni)
                acc[mi][ni] = __builtin_amdgcn_mfma_f32_16x16x32_bf16(a[kk][mi], b[kk][ni], acc[mi][ni], 0, 0, 0);
}

#define PIPE_READS_RELEASE(Ac, Bc)                                   \
    bf16x8 a[2][4], b[2][4];                                         \
    read_frags(Ac, Bc, a, b, wave, lane);                            \
    __builtin_amdgcn_sched_barrier(0);                               \
    asm volatile("s_waitcnt lgkmcnt(0)" ::: "memory");               \
    __builtin_amdgcn_sched_barrier(0);                               \
    __builtin_amdgcn_s_barrier();                                    \
    __builtin_amdgcn_sched_barrier(0);

#define PIPE_MFMA()                                                  \
    __builtin_amdgcn_s_setprio(1);                                   \
    mfma_frags(a, b, acc);                                           \
    __builtin_amdgcn_s_setprio(0);

#define PIPE_TAIL(N)                                                 \
    __builtin_amdgcn_sched_barrier(0);                               \
    asm volatile("s_waitcnt vmcnt(" #N ")" ::: "memory");            \
    __builtin_amdgcn_s_barrier();                                    \
    __builtin_amdgcn_sched_barrier(0);

__device__ __forceinline__ void kloop_pipe(const ushort* __restrict__ xn,
        int rowBase, int colBase, f32x4 (&acc)[4][4],
        ushort* As0, ushort* Bs0, ushort* As1, ushort* Bs1, int wave, int lane)
{
    stage_tiles(xn, rowBase, colBase, 0,  As0, Bs0, wave, lane);
    stage_tiles(xn, rowBase, colBase, 64, As1, Bs1, wave, lane);
    asm volatile("s_waitcnt vmcnt(8)" ::: "memory");
    __builtin_amdgcn_s_barrier();
    __builtin_amdgcn_sched_barrier(0);
    {
        PIPE_READS_RELEASE(As0, Bs0)
        stage_tiles(xn, rowBase, colBase, 128, As0, Bs0, wave, lane);
        PIPE_MFMA()
        PIPE_TAIL(8)
    }
    {
        PIPE_READS_RELEASE(As1, Bs1)
        stage_tiles(xn, rowBase, colBase, 192, As1, Bs1, wave, lane);
        PIPE_MFMA()
        PIPE_TAIL(8)
    }
    {
        PIPE_READS_RELEASE(As0, Bs0)
        PIPE_MFMA()
        PIPE_TAIL(0)
    }
    {
        PIPE_READS_RELEASE(As1, Bs1)
        PIPE_MFMA()
    }
}

// ---------------- Kernel C: upper-tri 128-tiles -> pD partials (round-4 core)
__global__ __launch_bounds__(256) void phase1_gemm(const ushort* __restrict__ xn,
        const int* __restrict__ labelPerm, float* __restrict__ pD)
{
    __shared__ __align__(16) char pool[65536];
    ushort* As0 = (ushort*)(pool);
    ushort* Bs0 = (ushort*)(pool + 16384);
    ushort* As1 = (ushort*)(pool + 32768);
    ushort* Bs1 = (ushort*)(pool + 49152);
    float* rowD = (float*)pool;            // [128][32], aliases pool post-release
    float* colD = (float*)(pool + 16384);  // [128][8]
    __shared__ int labLDS[256];

    const int tid = threadIdx.x;
    const int wave = tid >> 6, lane = tid & 63;

    int t = blockIdx.x, bi = 0;
    while (t >= 64 - bi) { t -= 64 - bi; ++bi; }
    const int bj = bi + t;
    const bool isDiag = (bi == bj);
    const int rowBase = bi * 128, colBase = bj * 128;

    labLDS[tid] = labelPerm[(tid < 128) ? (rowBase + tid) : (colBase + tid - 128)];
    __builtin_amdgcn_sched_barrier(0);

    f32x4 acc[4][4] = {};
    kloop_pipe(xn, rowBase, colBase, acc, As0, Bs0, As1, Bs1, wave, lane);

    const int wr = wave >> 1, wc = wave & 1;
    const int lrow = lane & 15, lgrp = lane >> 4;
    float colAcc[4] = {0.f, 0.f, 0.f, 0.f};
    #pragma unroll
    for (int mi = 0; mi < 4; ++mi) {
        #pragma unroll
        for (int reg = 0; reg < 4; ++reg) {
            const int tr = wr * 64 + mi * 16 + lgrp * 4 + reg;
            const int rl = labLDS[tr];
            float rowAcc = 0.f;
            #pragma unroll
            for (int ni = 0; ni < 4; ++ni) {
                const int tc = wc * 64 + ni * 16 + lrow;
                float e = __builtin_amdgcn_exp2f(acc[mi][ni][reg] * EXPC);
                float ed = (rl != labLDS[128 + tc]) ? e : 0.f;
                rowAcc += ed;
                colAcc[ni] += ed;
            }
            rowD[tr * 32 + wc * 16 + lrow] = rowAcc;
        }
    }
    if (!isDiag) {
        #pragma unroll
        for (int ni = 0; ni < 4; ++ni) {
            const int tc = wc * 64 + ni * 16 + lrow;
            colD[tc * 8 + wr * 4 + lgrp] = colAcc[ni];
        }
    }
    __syncthreads();

    if (tid < 128) {
        const float* p = rowD + tid * 32;
        float s = 0.f;
        #pragma unroll
        for (int k = 0; k < 8; ++k) {
            f32x4 v = *reinterpret_cast<const f32x4*>(p + k * 4);
            s += v[0] + v[1] + v[2] + v[3];
        }
        pD[(size_t)bj * N_ROWS + rowBase + tid] = s;
    } else if (!isDiag) {
        const int c2 = tid - 128;
        const float* p = colD + c2 * 8;
        f32x4 v0 = *reinterpret_cast<const f32x4*>(p);
        f32x4 v1 = *reinterpret_cast<const f32x4*>(p + 4);
        pD[(size_t)bi * N_ROWS + colBase + c2] =
            v0[0] + v0[1] + v0[2] + v0[3] + v1[0] + v1[1] + v1[2] + v1[3];
    }
}

// ---------------- Kernel D: same-class tiles -> log terms.
// Fused: per-block Darr gather (kills phase2) + last-block final reduction
// (kills phase4). One block per tile slot; empty slots just arrive.
__global__ __launch_bounds__(256) void phase3_loss(const ushort* __restrict__ xn,
        const float* __restrict__ pD, const int* __restrict__ classStart,
        const int* __restrict__ cumTiles, float* __restrict__ partial,
        unsigned int* __restrict__ counter, float* __restrict__ out)
{
    __shared__ __align__(16) char pool[65536];
    ushort* As0 = (ushort*)(pool);
    ushort* Bs0 = (ushort*)(pool + 16384);
    ushort* As1 = (ushort*)(pool + 32768);
    ushort* Bs1 = (ushort*)(pool + 49152);
    __shared__ float redF[256];
    __shared__ float DarrH[256];
    __shared__ float DarrL[128];
    __shared__ int   meta[22];
    __shared__ int   lastFlag;

    const int tid = threadIdx.x;
    const int wave = tid >> 6, lane = tid & 63;
    const int b = blockIdx.x;

    if (tid < 11) { meta[tid] = classStart[tid]; meta[11 + tid] = cumTiles[tid]; }
    __syncthreads();
    const int nTiles = meta[11 + 10];

    if (b < nTiles) {
        int c = 0;
        while (c < 9 && b >= meta[11 + c + 1]) ++c;
        const int s = meta[c], e = meta[c + 1];
        const int nc = e - s;
        const int tps = (nc + 127) >> 7;
        const int lt = b - meta[11 + c];
        const int ti = lt / tps, tj = lt - ti * tps;
        const int rowBase = s + ti * 128, colBase = s + tj * 128;

        // per-block Darr: 256 threads, 2 slice-halves per row (fixed order)
        {
            const int r = rowBase + (tid & 127);
            const int half = tid >> 7;
            float d = 0.f;
            #pragma unroll 4
            for (int sl = half * 32; sl < half * 32 + 32; ++sl)
                d += pD[(size_t)sl * N_ROWS + r];
            DarrH[(tid & 127) * 2 + half] = d;
        }
        __syncthreads();
        if (tid < 128) DarrL[tid] = DarrH[tid * 2] + DarrH[tid * 2 + 1];
        asm volatile("s_waitcnt vmcnt(0)" ::: "memory");   // clean vmcnt ledger
        __syncthreads();

        f32x4 acc[4][4] = {};
        kloop_pipe(xn, rowBase, colBase, acc, As0, Bs0, As1, Bs1, wave, lane);

        const int wr = wave >> 1, wc = wave & 1;
        const int lrow = lane & 15, lgrp = lane >> 4;
        float lsum = 0.f;
        #pragma unroll
        for (int mi = 0; mi < 4; ++mi) {
            #pragma unroll
            for (int reg = 0; reg < 4; ++reg) {
                const int tr = wr * 64 + mi * 16 + lgrp * 4 + reg;
                const int r = rowBase + tr;
                if (r < e) {
                    const float Dr = DarrL[tr];
                    #pragma unroll
                    for (int ni = 0; ni < 4; ++ni) {
                        const int cg = colBase + wc * 64 + ni * 16 + lrow;
                        if (cg < e && cg != r) {
                            float sim = acc[mi][ni][reg];
                            float ev = __builtin_amdgcn_exp2f(sim * EXPC);
                            lsum += __logf(ev + Dr) - TEMP_INV * sim;
                        }
                    }
                }
            }
        }
        redF[tid] = lsum;
        __syncthreads();
        for (int st = 128; st > 0; st >>= 1) {
            if (tid < st) redF[tid] += redF[tid + st];
            __syncthreads();
        }
        if (tid == 0) partial[b] = redF[0];
    }

    // -------- tail: last-block-done deterministic final reduction --------
    __threadfence();
    if (tid == 0) {
        unsigned int old = atomicAdd(counter, 1u);
        lastFlag = (old == (unsigned int)(gridDim.x - 1)) ? 1 : 0;
    }
    __syncthreads();
    if (lastFlag) {
        __threadfence();
        float s = 0.f;
        for (int i = tid; i < nTiles; i += 256) s += partial[i];
        redF[tid] = s;
        __syncthreads();
        for (int st = 128; st > 0; st >>= 1) {
            if (tid < st) redF[tid] += redF[tid + st];
            __syncthreads();
        }
        if (tid == 0) out[0] = redF[0] * (1.0f / 16384.0f);
    }
}

extern "C" void kernel_launch(void* const* d_in, const int* in_sizes, int n_in,
                              void* d_out, int out_size, void* d_ws, size_t ws_size,
                              hipStream_t stream)
{
    const float* logits = (const float*)d_in[0];
    const int*   label  = (const int*)d_in[1];
    float* out = (float*)d_out;

    char* ws = (char*)d_ws;
    ushort*       xn        = (ushort*)(ws);                          // 4 MB
    float*        pD        = (float*)(ws + (4u << 20));              // 2 MB
    int*          perm      = (int*)(ws + (6u << 20));                // 32 KB
    int*          labelPerm = (int*)(ws + (6u << 20) + (32u << 10));  // 32 KB
    int*          classStart= (int*)(ws + (6u << 20) + (64u << 10));  // 64 B
    int*          cumTiles  = (int*)(ws + (6u << 20) + (64u << 10) + 256); // 64 B
    float*        partial   = (float*)(ws + (6u << 20) + (128u << 10));    // 16 KB
    unsigned int* counter   = (unsigned int*)(ws + (6u << 20) + (192u << 10)); // 4 B

    hipLaunchKernelGGL(build_perm, dim3(1), dim3(1024), 0, stream,
                       label, perm, labelPerm, classStart, cumTiles, counter);
    hipLaunchKernelGGL(normalize_rows, dim3(2048), dim3(256), 0, stream,
                       logits, perm, xn);
    hipLaunchKernelGGL(phase1_gemm, dim3(2080), dim3(256), 0, stream,
                       xn, labelPerm, pD);
    hipLaunchKernelGGL(phase3_loss, dim3(4096), dim3(256), 0, stream,
                       xn, pD, classStart, cumTiles, partial, counter, out);
}

// Round 8
// 70.771 us; speedup vs baseline: 4.2843x; 4.2843x over previous
//
#include <hip/hip_runtime.h>
#include <cstdint>
#include <cstddef>

typedef __bf16 bf16x8 __attribute__((ext_vector_type(8)));
typedef float  f32x4  __attribute__((ext_vector_type(4)));
typedef long long i64;
typedef unsigned char uchar;

#define N_ROWS 8192
#define KDIM   256
#define TEMP_INV 2.0f
#define LOG2E  1.4426950408889634f
#define EXPC   (TEMP_INV * LOG2E)

__device__ __forceinline__ ushort f2bf(float x) {
    uint32_t u = __float_as_uint(x);
    u += 0x7fffu + ((u >> 16) & 1u);
    return (ushort)(u >> 16);
}

// ---------------- Kernel A: label ranking / permutation (1 block, 1024 thr)
__global__ __launch_bounds__(1024) void build_perm(const int* __restrict__ label,
        int* __restrict__ perm, int* __restrict__ labelPerm,
        int* __restrict__ classStart, int* __restrict__ cumTiles)
{
    __shared__ unsigned short lcnt[1024][10];
    __shared__ int cstart[11];
    __shared__ int ccount[10];
    const int tid = threadIdx.x;
    const int wave = tid >> 6, lane = tid & 63;

    int lab[8];
    #pragma unroll
    for (int j = 0; j < 8; ++j) {
        int c = label[tid + j * 1024];
        lab[j] = (c < 0) ? 0 : (c > 9 ? 9 : c);
    }
    unsigned short loc[10] = {0,0,0,0,0,0,0,0,0,0};
    #pragma unroll
    for (int j = 0; j < 8; ++j) loc[lab[j]]++;
    #pragma unroll
    for (int c = 0; c < 10; ++c) lcnt[tid][c] = loc[c];
    __syncthreads();

    if (wave < 10) {  // one wave per class: scan 1024 counts
        const int c = wave;
        int s[16]; int tot = 0;
        #pragma unroll
        for (int m = 0; m < 16; ++m) { s[m] = lcnt[lane * 16 + m][c]; tot += s[m]; }
        int incl = tot;
        #pragma unroll
        for (int d = 1; d < 64; d <<= 1) {
            int up = __shfl_up(incl, d, 64);
            if (lane >= d) incl += up;
        }
        int run = incl - tot;
        #pragma unroll
        for (int m = 0; m < 16; ++m) { lcnt[lane * 16 + m][c] = (unsigned short)run; run += s[m]; }
        if (lane == 63) ccount[c] = incl;
    }
    __syncthreads();

    if (tid == 0) {
        int run = 0, runT = 0;
        for (int c = 0; c < 10; ++c) {
            cstart[c] = run; classStart[c] = run;
            int tpc = (ccount[c] + 127) >> 7;
            cumTiles[c] = runT;
            run  += ccount[c];
            runT += tpc * tpc;
        }
        cstart[10] = run; classStart[10] = run; cumTiles[10] = runT;
    }
    __syncthreads();

    int ofs[10];
    #pragma unroll
    for (int c = 0; c < 10; ++c) ofs[c] = lcnt[tid][c];
    #pragma unroll
    for (int j = 0; j < 8; ++j) {
        int c = lab[j];
        int pos = cstart[c] + ofs[c]++;
        perm[pos] = tid + j * 1024;
        labelPerm[pos] = c;
    }
}

// ---------------- Kernel B: normalize + permute + bf16 AND fp8 casts --------
__global__ __launch_bounds__(256) void normalize_rows(const float* __restrict__ logits,
        const int* __restrict__ perm, ushort* __restrict__ xn, uchar* __restrict__ xn8)
{
    const int p = blockIdx.x * 4 + (threadIdx.x >> 6);
    const int lane = threadIdx.x & 63;
    const int old = perm[p];
    float4 v = reinterpret_cast<const float4*>(logits + (size_t)old * KDIM)[lane];
    float ss = v.x*v.x + v.y*v.y + v.z*v.z + v.w*v.w;
    #pragma unroll
    for (int off = 32; off >= 1; off >>= 1) ss += __shfl_xor(ss, off, 64);
    float inv = 1.0f / fmaxf(sqrtf(ss), 1e-8f);
    float x0 = v.x * inv, x1 = v.y * inv, x2 = v.z * inv, x3 = v.w * inv;
    ushort4 o;
    o.x = f2bf(x0); o.y = f2bf(x1); o.z = f2bf(x2); o.w = f2bf(x3);
    reinterpret_cast<ushort4*>(xn + (size_t)p * KDIM)[lane] = o;
    int pk = __builtin_amdgcn_cvt_pk_fp8_f32(x0, x1, 0, false);
    pk     = __builtin_amdgcn_cvt_pk_fp8_f32(x2, x3, pk, true);
    reinterpret_cast<unsigned int*>(xn8 + (size_t)p * KDIM)[lane] = (unsigned int)pk;
}

// ================= fp8 4-wave 128-tile core (phase1) =================
// LDS tile: 128 rows x 64 B (BK=64 fp8). 16B chunk swizzle: slot = c ^ (row&3),
// linear LDS dest + pre-swizzled global source (rule #21).
__device__ __forceinline__ void stage_pair_fp8(const uchar* __restrict__ xn8,
        int rowBase, int colBase, int kb, uchar* As, uchar* Bs, int wave, int lane)
{
    #pragma unroll
    for (int it = 0; it < 2; ++it) {
        int ci = it * 256 + wave * 64 + lane;          // 16B chunk in [0,512)
        int row = ci >> 2;
        int c = (ci & 3) ^ (row & 3);
        const uchar* gA = xn8 + (size_t)(rowBase + row) * KDIM + kb + c * 16;
        const uchar* gB = xn8 + (size_t)(colBase + row) * KDIM + kb + c * 16;
        uchar* lA = As + (size_t)ci * 16;
        uchar* lB = Bs + (size_t)ci * 16;
        __builtin_amdgcn_global_load_lds((const __attribute__((address_space(1))) void*)gA,
                                         (__attribute__((address_space(3))) void*)lA, 16, 0, 0);
        __builtin_amdgcn_global_load_lds((const __attribute__((address_space(1))) void*)gB,
                                         (__attribute__((address_space(3))) void*)lB, 16, 0, 0);
    }
}

__device__ __forceinline__ void read_frags8(const uchar* As, const uchar* Bs,
        i64 (&a)[2][4], i64 (&b)[2][4], int wave, int lane)
{
    const int wr = wave >> 1, wc = wave & 1;
    const int lrow = lane & 15, kgrp = lane >> 4;
    const int ch = kgrp >> 1, half = kgrp & 1;
    #pragma unroll
    for (int kk = 0; kk < 2; ++kk) {
        const int c16 = kk * 2 + ch;                   // logical 16B chunk
        #pragma unroll
        for (int mi = 0; mi < 4; ++mi) {
            const int row = wr*64 + mi*16 + lrow;
            a[kk][mi] = *reinterpret_cast<const i64*>(As + (size_t)row * 64 + ((c16 ^ (row & 3)) * 16) + half * 8);
        }
        #pragma unroll
        for (int ni = 0; ni < 4; ++ni) {
            const int row = wc*64 + ni*16 + lrow;
            b[kk][ni] = *reinterpret_cast<const i64*>(Bs + (size_t)row * 64 + ((c16 ^ (row & 3)) * 16) + half * 8);
        }
    }
}

__device__ __forceinline__ void mfma_frags8(i64 (&a)[2][4], i64 (&b)[2][4], f32x4 (&acc)[4][4])
{
    #pragma unroll
    for (int kk = 0; kk < 2; ++kk)
        #pragma unroll
        for (int mi = 0; mi < 4; ++mi)
            #pragma unroll
            for (int ni = 0; ni < 4; ++ni)
                acc[mi][ni] = __builtin_amdgcn_mfma_f32_16x16x32_fp8_fp8(a[kk][mi], b[kk][ni], acc[mi][ni], 0, 0, 0);
}

#define PIPE8_READS_RELEASE(Ac, Bc)                                  \
    i64 a[2][4], b[2][4];                                            \
    read_frags8(Ac, Bc, a, b, wave, lane);                           \
    __builtin_amdgcn_sched_barrier(0);                               \
    asm volatile("s_waitcnt lgkmcnt(0)" ::: "memory");               \
    __builtin_amdgcn_sched_barrier(0);                               \
    __builtin_amdgcn_s_barrier();                                    \
    __builtin_amdgcn_sched_barrier(0);

#define PIPE8_MFMA()                                                 \
    __builtin_amdgcn_s_setprio(1);                                   \
    mfma_frags8(a, b, acc);                                          \
    __builtin_amdgcn_s_setprio(0);

#define PIPE8_TAIL(N)                                                \
    __builtin_amdgcn_sched_barrier(0);                               \
    asm volatile("s_waitcnt vmcnt(" #N ")" ::: "memory");            \
    __builtin_amdgcn_s_barrier();                                    \
    __builtin_amdgcn_sched_barrier(0);

__device__ __forceinline__ void kloop_fp8(const uchar* __restrict__ xn8,
        int rowBase, int colBase, f32x4 (&acc)[4][4],
        uchar* As0, uchar* Bs0, uchar* As1, uchar* Bs1, int wave, int lane)
{
    stage_pair_fp8(xn8, rowBase, colBase, 0,  As0, Bs0, wave, lane);  // 4 loads
    stage_pair_fp8(xn8, rowBase, colBase, 64, As1, Bs1, wave, lane);  // 4 loads
    asm volatile("s_waitcnt vmcnt(4)" ::: "memory");                  // S0 landed
    __builtin_amdgcn_s_barrier();
    __builtin_amdgcn_sched_barrier(0);
    {
        PIPE8_READS_RELEASE(As0, Bs0)
        stage_pair_fp8(xn8, rowBase, colBase, 128, As0, Bs0, wave, lane);
        PIPE8_MFMA()
        PIPE8_TAIL(4)                                                 // S1 landed
    }
    {
        PIPE8_READS_RELEASE(As1, Bs1)
        stage_pair_fp8(xn8, rowBase, colBase, 192, As1, Bs1, wave, lane);
        PIPE8_MFMA()
        PIPE8_TAIL(4)                                                 // S2 landed
    }
    {
        PIPE8_READS_RELEASE(As0, Bs0)
        PIPE8_MFMA()
        PIPE8_TAIL(0)                                                 // S3 landed
    }
    {
        PIPE8_READS_RELEASE(As1, Bs1)   // release barrier frees pool for epilogue
        PIPE8_MFMA()
    }
}

// ---------------- Kernel C: upper-tri 128-tiles (fp8) -> pD partials --------
__global__ __launch_bounds__(256, 4) void phase1_gemm(const uchar* __restrict__ xn8,
        const int* __restrict__ labelPerm, float* __restrict__ pD)
{
    __shared__ __align__(16) char pool[32768];
    uchar* As0 = (uchar*)(pool);
    uchar* Bs0 = (uchar*)(pool + 8192);
    uchar* As1 = (uchar*)(pool + 16384);
    uchar* Bs1 = (uchar*)(pool + 24576);
    float* rowD = (float*)pool;            // [128][32], aliases pool post-release
    float* colD = (float*)(pool + 16384);  // [128][8]
    __shared__ int labLDS[256];

    const int tid = threadIdx.x;
    const int wave = tid >> 6, lane = tid & 63;

    int t = blockIdx.x, bi = 0;
    while (t >= 64 - bi) { t -= 64 - bi; ++bi; }
    const int bj = bi + t;
    const bool isDiag = (bi == bj);
    const int rowBase = bi * 128, colBase = bj * 128;

    labLDS[tid] = labelPerm[(tid < 128) ? (rowBase + tid) : (colBase + tid - 128)];
    __builtin_amdgcn_sched_barrier(0);

    f32x4 acc[4][4] = {};
    kloop_fp8(xn8, rowBase, colBase, acc, As0, Bs0, As1, Bs1, wave, lane);

    const int wr = wave >> 1, wc = wave & 1;
    const int lrow = lane & 15, lgrp = lane >> 4;
    float colAcc[4] = {0.f, 0.f, 0.f, 0.f};
    #pragma unroll
    for (int mi = 0; mi < 4; ++mi) {
        #pragma unroll
        for (int reg = 0; reg < 4; ++reg) {
            const int tr = wr * 64 + mi * 16 + lgrp * 4 + reg;
            const int rl = labLDS[tr];
            float rowAcc = 0.f;
            #pragma unroll
            for (int ni = 0; ni < 4; ++ni) {
                const int tc = wc * 64 + ni * 16 + lrow;
                float e = __builtin_amdgcn_exp2f(acc[mi][ni][reg] * EXPC);
                float ed = (rl != labLDS[128 + tc]) ? e : 0.f;
                rowAcc += ed;
                colAcc[ni] += ed;
            }
            rowD[tr * 32 + wc * 16 + lrow] = rowAcc;
        }
    }
    if (!isDiag) {
        #pragma unroll
        for (int ni = 0; ni < 4; ++ni) {
            const int tc = wc * 64 + ni * 16 + lrow;
            colD[tc * 8 + wr * 4 + lgrp] = colAcc[ni];
        }
    }
    __syncthreads();

    if (tid < 128) {
        const float* p = rowD + tid * 32;
        float s = 0.f;
        #pragma unroll
        for (int k = 0; k < 8; ++k) {
            f32x4 v = *reinterpret_cast<const f32x4*>(p + k * 4);
            s += v[0] + v[1] + v[2] + v[3];
        }
        pD[(size_t)bj * N_ROWS + rowBase + tid] = s;
    } else if (!isDiag) {
        const int c2 = tid - 128;
        const float* p = colD + c2 * 8;
        f32x4 v0 = *reinterpret_cast<const f32x4*>(p);
        f32x4 v1 = *reinterpret_cast<const f32x4*>(p + 4);
        pD[(size_t)bi * N_ROWS + colBase + c2] =
            v0[0] + v0[1] + v0[2] + v0[3] + v1[0] + v1[1] + v1[2] + v1[3];
    }
}

// ================= bf16 4-wave 128-tile core (phase3, R4-validated) =========
__device__ __forceinline__ void stage_tiles(const ushort* __restrict__ xn,
        int rowBase, int colBase, int kb, ushort* As, ushort* Bs, int wave, int lane)
{
    #pragma unroll
    for (int it = 0; it < 4; ++it) {
        int ci = it * 256 + wave * 64 + lane;
        int row = ci >> 3;
        int c = (ci & 7) ^ (row & 7);
        const ushort* gA = xn + (size_t)(rowBase + row) * KDIM + kb + c * 8;
        const ushort* gB = xn + (size_t)(colBase + row) * KDIM + kb + c * 8;
        ushort* lA = As + (size_t)(it * 256 + wave * 64) * 8;
        ushort* lB = Bs + (size_t)(it * 256 + wave * 64) * 8;
        __builtin_amdgcn_global_load_lds((const __attribute__((address_space(1))) void*)gA,
                                         (__attribute__((address_space(3))) void*)lA, 16, 0, 0);
        __builtin_amdgcn_global_load_lds((const __attribute__((address_space(1))) void*)gB,
                                         (__attribute__((address_space(3))) void*)lB, 16, 0, 0);
    }
}

__device__ __forceinline__ void read_frags(const ushort* As, const ushort* Bs,
        bf16x8 (&a)[2][4], bf16x8 (&b)[2][4], int wave, int lane)
{
    const int wr = wave >> 1, wc = wave & 1;
    const int lrow = lane & 15, kgrp = lane >> 4;
    #pragma unroll
    for (int kk = 0; kk < 2; ++kk) {
        const int c = kk * 4 + kgrp;
        #pragma unroll
        for (int mi = 0; mi < 4; ++mi) {
            const int row = wr*64 + mi*16 + lrow;
            a[kk][mi] = *reinterpret_cast<const bf16x8*>(As + (size_t)row * 64 + ((c ^ (row & 7)) * 8));
        }
        #pragma unroll
        for (int ni = 0; ni < 4; ++ni) {
            const int row = wc*64 + ni*16 + lrow;
            b[kk][ni] = *reinterpret_cast<const bf16x8*>(Bs + (size_t)row * 64 + ((c ^ (row & 7)) * 8));
        }
    }
}

__device__ __forceinline__ void mfma_frags(bf16x8 (&a)[2][4], bf16x8 (&b)[2][4],
                                           f32x4 (&acc)[4][4])
{
    #pragma unroll
    for (int kk = 0; kk < 2; ++kk)
        #pragma unroll
        for (int mi = 0; mi < 4; ++mi)
            #pragma unroll
            for (int ni = 0; ni < 4; ++ni)
                acc[mi][ni] = __builtin_amdgcn_mfma_f32_16x16x32_bf16(a[kk][mi], b[kk][ni], acc[mi][ni], 0, 0, 0);
}

#define PIPE_READS_RELEASE(Ac, Bc)                                   \
    bf16x8 a[2][4], b[2][4];                                         \
    read_frags(Ac, Bc, a, b, wave, lane);                            \
    __builtin_amdgcn_sched_barrier(0);                               \
    asm volatile("s_waitcnt lgkmcnt(0)" ::: "memory");               \
    __builtin_amdgcn_sched_barrier(0);                               \
    __builtin_amdgcn_s_barrier();                                    \
    __builtin_amdgcn_sched_barrier(0);

#define PIPE_MFMA()                                                  \
    __builtin_amdgcn_s_setprio(1);                                   \
    mfma_frags(a, b, acc);                                           \
    __builtin_amdgcn_s_setprio(0);

#define PIPE_TAIL(N)                                                 \
    __builtin_amdgcn_sched_barrier(0);                               \
    asm volatile("s_waitcnt vmcnt(" #N ")" ::: "memory");            \
    __builtin_amdgcn_s_barrier();                                    \
    __builtin_amdgcn_sched_barrier(0);

__device__ __forceinline__ void kloop_pipe(const ushort* __restrict__ xn,
        int rowBase, int colBase, f32x4 (&acc)[4][4],
        ushort* As0, ushort* Bs0, ushort* As1, ushort* Bs1, int wave, int lane)
{
    stage_tiles(xn, rowBase, colBase, 0,  As0, Bs0, wave, lane);
    stage_tiles(xn, rowBase, colBase, 64, As1, Bs1, wave, lane);
    asm volatile("s_waitcnt vmcnt(8)" ::: "memory");
    __builtin_amdgcn_s_barrier();
    __builtin_amdgcn_sched_barrier(0);
    {
        PIPE_READS_RELEASE(As0, Bs0)
        stage_tiles(xn, rowBase, colBase, 128, As0, Bs0, wave, lane);
        PIPE_MFMA()
        PIPE_TAIL(8)
    }
    {
        PIPE_READS_RELEASE(As1, Bs1)
        stage_tiles(xn, rowBase, colBase, 192, As1, Bs1, wave, lane);
        PIPE_MFMA()
        PIPE_TAIL(8)
    }
    {
        PIPE_READS_RELEASE(As0, Bs0)
        PIPE_MFMA()
        PIPE_TAIL(0)
    }
    {
        PIPE_READS_RELEASE(As1, Bs1)
        PIPE_MFMA()
    }
}

// ---------------- Kernel D: same-class tiles -> log terms (+ Darr gather) ---
__global__ __launch_bounds__(256) void phase3_loss(const ushort* __restrict__ xn,
        const float* __restrict__ pD, const int* __restrict__ classStart,
        const int* __restrict__ cumTiles, float* __restrict__ partial)
{
    __shared__ __align__(16) char pool[65536];
    ushort* As0 = (ushort*)(pool);
    ushort* Bs0 = (ushort*)(pool + 16384);
    ushort* As1 = (ushort*)(pool + 32768);
    ushort* Bs1 = (ushort*)(pool + 49152);
    __shared__ float redF[256];
    __shared__ float DarrH[256];
    __shared__ float DarrL[128];
    __shared__ int   meta[22];

    const int tid = threadIdx.x;
    const int wave = tid >> 6, lane = tid & 63;
    const int b = blockIdx.x;

    if (tid < 11) { meta[tid] = classStart[tid]; meta[11 + tid] = cumTiles[tid]; }
    __syncthreads();
    const int nTiles = meta[11 + 10];
    if (b >= nTiles) return;

    int c = 0;
    while (c < 9 && b >= meta[11 + c + 1]) ++c;
    const int s = meta[c], e = meta[c + 1];
    const int nc = e - s;
    const int tps = (nc + 127) >> 7;
    const int lt = b - meta[11 + c];
    const int ti = lt / tps, tj = lt - ti * tps;
    const int rowBase = s + ti * 128, colBase = s + tj * 128;

    // per-block Darr gather (fixed order; kills the phase2 kernel)
    {
        const int r = rowBase + (tid & 127);
        const int half = tid >> 7;
        float d = 0.f;
        #pragma unroll 4
        for (int sl = half * 32; sl < half * 32 + 32; ++sl)
            d += pD[(size_t)sl * N_ROWS + r];
        DarrH[(tid & 127) * 2 + half] = d;
    }
    __syncthreads();
    if (tid < 128) DarrL[tid] = DarrH[tid * 2] + DarrH[tid * 2 + 1];
    asm volatile("s_waitcnt vmcnt(0)" ::: "memory");   // clean vmcnt ledger
    __syncthreads();

    f32x4 acc[4][4] = {};
    kloop_pipe(xn, rowBase, colBase, acc, As0, Bs0, As1, Bs1, wave, lane);

    const int wr = wave >> 1, wc = wave & 1;
    const int lrow = lane & 15, lgrp = lane >> 4;
    float lsum = 0.f;
    #pragma unroll
    for (int mi = 0; mi < 4; ++mi) {
        #pragma unroll
        for (int reg = 0; reg < 4; ++reg) {
            const int tr = wr * 64 + mi * 16 + lgrp * 4 + reg;
            const int r = rowBase + tr;
            if (r < e) {
                const float Dr = DarrL[tr];
                #pragma unroll
                for (int ni = 0; ni < 4; ++ni) {
                    const int cg = colBase + wc * 64 + ni * 16 + lrow;
                    if (cg < e && cg != r) {
                        float sim = acc[mi][ni][reg];
                        float ev = __builtin_amdgcn_exp2f(sim * EXPC);
                        lsum += __logf(ev + Dr) - TEMP_INV * sim;
                    }
                }
            }
        }
    }
    redF[tid] = lsum;
    __syncthreads();
    for (int st = 128; st > 0; st >>= 1) {
        if (tid < st) redF[tid] += redF[tid + st];
        __syncthreads();
    }
    if (tid == 0) partial[b] = redF[0];
}

// ---------------- Kernel E: deterministic final reduction + scale ----------
__global__ void phase4_final(const float* __restrict__ partial, const int* __restrict__ cumTiles,
                             float* __restrict__ out)
{
    __shared__ float red[256];
    const int tid = threadIdx.x;
    const int nTiles = cumTiles[10];
    float s = 0.f;
    for (int i = tid; i < nTiles; i += 256) s += partial[i];
    red[tid] = s;
    __syncthreads();
    for (int st = 128; st > 0; st >>= 1) {
        if (tid < st) red[tid] += red[tid + st];
        __syncthreads();
    }
    if (tid == 0) out[0] = red[0] * (1.0f / 16384.0f);
}

extern "C" void kernel_launch(void* const* d_in, const int* in_sizes, int n_in,
                              void* d_out, int out_size, void* d_ws, size_t ws_size,
                              hipStream_t stream)
{
    const float* logits = (const float*)d_in[0];
    const int*   label  = (const int*)d_in[1];
    float* out = (float*)d_out;

    char* ws = (char*)d_ws;
    ushort* xn        = (ushort*)(ws);                          // 4 MB
    uchar*  xn8       = (uchar*)(ws + (4u << 20));              // 2 MB
    float*  pD        = (float*)(ws + (6u << 20));              // 2 MB
    int*    perm      = (int*)(ws + (8u << 20));                // 32 KB
    int*    labelPerm = (int*)(ws + (8u << 20) + (32u << 10));  // 32 KB
    int*    classStart= (int*)(ws + (8u << 20) + (64u << 10));  // 64 B
    int*    cumTiles  = (int*)(ws + (8u << 20) + (64u << 10) + 256); // 64 B
    float*  partial   = (float*)(ws + (8u << 20) + (128u << 10));    // 16 KB

    hipLaunchKernelGGL(build_perm, dim3(1), dim3(1024), 0, stream,
                       label, perm, labelPerm, classStart, cumTiles);
    hipLaunchKernelGGL(normalize_rows, dim3(2048), dim3(256), 0, stream,
                       logits, perm, xn, xn8);
    hipLaunchKernelGGL(phase1_gemm, dim3(2080), dim3(256), 0, stream,
                       xn8, labelPerm, pD);
    hipLaunchKernelGGL(phase3_loss, dim3(4096), dim3(256), 0, stream,
                       xn, pD, classStart, cumTiles, partial);
    hipLaunchKernelGGL(phase4_final, dim3(1), dim3(256), 0, stream,
                       partial, cumTiles, out);
}